// Round 1
// 19453.357 us; speedup vs baseline: 1.4064x; 1.4064x over previous
//
#include <hip/hip_runtime.h>
#include <stdint.h>

typedef _Float16 f16;
typedef _Float16 h8  __attribute__((ext_vector_type(8)));
typedef _Float16 h4v __attribute__((ext_vector_type(4)));
typedef _Float16 h2v __attribute__((ext_vector_type(2)));
typedef float    fx4 __attribute__((ext_vector_type(4)));
typedef unsigned long long u64;

constexpr int HDIM   = 512;
constexpr int SEQT   = 256;
constexpr int NBATCH = 32;
constexpr int NCOL   = 4096;   // 2 dirs * 2048 gate rows

// ---- ws layout (bytes) ----
constexpr size_t OFF_E    = 0;            // 16 f32
constexpr size_t OFF_BIAS = 0x1000;       // 2 layers * 4096 f32
constexpr size_t OFF_WHH  = 0x10000;      // 4 * 2048*512 f16 (layer*2+dir)
constexpr size_t OFF_WIH0 = 0x00900000;   // 4096*512  f16
constexpr size_t OFF_WIH1 = 0x00D00000;   // 4096*1024 f16
constexpr size_t OFF_XF16 = 0x01500000;   // 8192*512  f16
constexpr size_t OFF_HS0  = 0x01D00000;   // 8192*1024 f16 (layer0 output)
constexpr size_t OFF_XP   = 0x02D00000;   // 8192*4096 f16
constexpr size_t OFF_HBUF = 0x06D00000;   // 2*2*32*512 f16 (double-buffered h)
constexpr size_t OFF_CTR  = 0x06D20000;   // 2 layers * [2][256][16] u32 = 64KB
constexpr size_t WS_NEED  = 0x06D30000;   // ~109.2 MB

__device__ __forceinline__ float sigmoidf_(float x) { return 1.0f / (1.0f + __expf(-x)); }
__device__ __forceinline__ float tanhf_(float x) {
  float e2 = __expf(2.0f * x);
  return (e2 - 1.0f) / (e2 + 1.0f);
}
__device__ __forceinline__ float dot8(h8 a, h8 b, float acc) {
#if __has_builtin(__builtin_amdgcn_fdot2)
  union U { h8 v; h2v p[4]; };
  U ua, ub; ua.v = a; ub.v = b;
  acc = __builtin_amdgcn_fdot2(ua.p[0], ub.p[0], acc, false);
  acc = __builtin_amdgcn_fdot2(ua.p[1], ub.p[1], acc, false);
  acc = __builtin_amdgcn_fdot2(ua.p[2], ub.p[2], acc, false);
  acc = __builtin_amdgcn_fdot2(ua.p[3], ub.p[3], acc, false);
#else
  #pragma unroll
  for (int i = 0; i < 8; i++) acc += (float)a[i] * (float)b[i];
#endif
  return acc;
}

// ---- e = renorm(emb_table[domain_id]) ----
__global__ void k_e(const float* __restrict__ emb, const int* __restrict__ dom,
                    float* __restrict__ e_out) {
  int lane = threadIdx.x;
  float v = 0.f;
  int d = *dom;
  if (lane < 16) v = emb[d * 16 + lane];
  float s = v * v;
  s += __shfl_xor(s, 1); s += __shfl_xor(s, 2);
  s += __shfl_xor(s, 4); s += __shfl_xor(s, 8);
  float n = sqrtf(s);
  float scale = fminf(1.0f, 1.0f / fmaxf(n, 1e-7f));
  if (lane < 16) e_out[lane] = v * scale;
}

// ---- Whh generation -> f16, 4 tensors of 2048x512, index = layer*2+dir ----
__global__ void k_gen_whh(const float* __restrict__ s0, const float* __restrict__ s1,
                          const float* __restrict__ s2, const float* __restrict__ s3,
                          const float* __restrict__ e, f16* __restrict__ out) {
  int idx = blockIdx.x * 256 + threadIdx.x;      // 4 * 1048576 total
  int t = idx >> 20;
  int rem = idx & 1048575;                        // g*512 + k
  const float* src = (t == 0) ? s0 : (t == 1) ? s1 : (t == 2) ? s2 : s3;
  const float4* w = (const float4*)(src + (size_t)rem * 16);
  float acc = 0.f;
  #pragma unroll
  for (int q = 0; q < 4; q++) {
    float4 wv = w[q];
    acc += wv.x * e[q*4+0] + wv.y * e[q*4+1] + wv.z * e[q*4+2] + wv.w * e[q*4+3];
  }
  out[idx] = (f16)acc;
}

// ---- Wih generation -> f16 rows n = dir*2048+g, cols K (ksh = log2 K) ----
__global__ void k_gen_wih(const float* __restrict__ sf, const float* __restrict__ sr,
                          const float* __restrict__ e, f16* __restrict__ out, int ksh) {
  int idx = blockIdx.x * 256 + threadIdx.x;      // 4096 * K total
  int n = idx >> ksh;
  int k = idx & ((1 << ksh) - 1);
  int dir = n >> 11;
  int g = n & 2047;
  const float* src = dir ? sr : sf;
  const float4* w = (const float4*)(src + ((size_t)(g << ksh) + k) * 16);
  float acc = 0.f;
  #pragma unroll
  for (int q = 0; q < 4; q++) {
    float4 wv = w[q];
    acc += wv.x * e[q*4+0] + wv.y * e[q*4+1] + wv.z * e[q*4+2] + wv.w * e[q*4+3];
  }
  out[idx] = (f16)acc;
}

// ---- bias generation: out[layer*4096 + dir*2048 + g] = (b_ih+b_hh)·e ----
__global__ void k_gen_bias(const float* bi0, const float* bh0, const float* bi0r, const float* bh0r,
                           const float* bi1, const float* bh1, const float* bi1r, const float* bh1r,
                           const float* __restrict__ e, float* __restrict__ out) {
  int idx = blockIdx.x * 256 + threadIdx.x;      // 8192
  int layer = idx >> 12;
  int dir = (idx >> 11) & 1;
  int g = idx & 2047;
  const float* a; const float* b;
  if (layer == 0) { a = dir ? bi0r : bi0; b = dir ? bh0r : bh0; }
  else            { a = dir ? bi1r : bi1; b = dir ? bh1r : bh1; }
  float acc = 0.f;
  #pragma unroll
  for (int m = 0; m < 16; m++) acc += (a[g*16 + m] + b[g*16 + m]) * e[m];
  out[idx] = acc;
}

// ---- fp32 -> fp16 cast (by float4) ----
__global__ void k_cast(const float* __restrict__ x, f16* __restrict__ out, int n4) {
  int i = blockIdx.x * 256 + threadIdx.x;
  if (i < n4) {
    float4 v = ((const float4*)x)[i];
    h4v o; o[0] = (f16)v.x; o[1] = (f16)v.y; o[2] = (f16)v.z; o[3] = (f16)v.w;
    *(h4v*)(out + (size_t)i * 4) = o;
  }
}

// ---- GEMM: C[m][n] = sum_k A[m][k]*B[n][k] + bias[n], A:(8192,K) B:(4096,K) f16, C f16 ----
__launch_bounds__(256, 2)
__global__ void k_gemm(const f16* __restrict__ A, const f16* __restrict__ B,
                       const float* __restrict__ bias, f16* __restrict__ C, int K) {
  __shared__ f16 Al[128 * 64];
  __shared__ f16 Bl[128 * 64];
  const int tid = threadIdx.x;
  const int m0 = blockIdx.x * 128;
  const int n0 = blockIdx.y * 128;
  const int lane = tid & 63, wave = tid >> 6;
  const int wm = (wave >> 1) * 64, wn = (wave & 1) * 64;
  const int quad = lane >> 4, m16 = lane & 15;
  const int r_row = tid >> 3;
  const int r_c8 = tid & 7;
  fx4 acc[4][4] = {};
  for (int kb = 0; kb < K; kb += 64) {
    h8 ra[4], rb[4];
    #pragma unroll
    for (int r = 0; r < 4; r++) {
      int row = r * 32 + r_row;
      int c8 = r_c8 ^ (row & 7);
      ra[r] = *(const h8*)(A + (size_t)(m0 + row) * K + kb + c8 * 8);
      rb[r] = *(const h8*)(B + (size_t)(n0 + row) * K + kb + c8 * 8);
    }
    __syncthreads();
    #pragma unroll
    for (int r = 0; r < 4; r++) {
      *(h8*)(Al + (r * 256 + tid) * 8) = ra[r];
      *(h8*)(Bl + (r * 256 + tid) * 8) = rb[r];
    }
    __syncthreads();
    #pragma unroll
    for (int kk = 0; kk < 2; kk++) {
      h8 af[4], bf[4];
      #pragma unroll
      for (int i = 0; i < 4; i++) {
        int arow = wm + i * 16 + m16;
        int slot = (kk * 4 + quad) ^ (arow & 7);
        af[i] = *(const h8*)(Al + arow * 64 + slot * 8);
      }
      #pragma unroll
      for (int j = 0; j < 4; j++) {
        int brow = wn + j * 16 + m16;
        int slot = (kk * 4 + quad) ^ (brow & 7);
        bf[j] = *(const h8*)(Bl + brow * 64 + slot * 8);
      }
      #pragma unroll
      for (int i = 0; i < 4; i++)
        #pragma unroll
        for (int j = 0; j < 4; j++)
          acc[i][j] = __builtin_amdgcn_mfma_f32_16x16x32_f16(af[i], bf[j], acc[i][j], 0, 0, 0);
    }
  }
  // epilogue: D[m = quad*4+reg][n = m16]
  #pragma unroll
  for (int j = 0; j < 4; j++) {
    int n = n0 + wn + j * 16 + m16;
    float bv = bias[n];
    #pragma unroll
    for (int i = 0; i < 4; i++) {
      int mbase = m0 + wm + i * 16 + quad * 4;
      #pragma unroll
      for (int rr = 0; rr < 4; rr++)
        C[(size_t)(mbase + rr) * NCOL + n] = (f16)(acc[i][j][rr] + bv);
    }
  }
}

// ---- persistent recurrence kernel: one launch per layer, grid 256 (co-resident) ----
// wg < 128: fwd, wg >= 128: bwd.  wg owns j-block [4w,4w+4) -> 16 gate rows.
//
// Sync protocol (NO __threadfence — fences were full L2 wbl2/inv walks, ~50us/step):
//   * h is exchanged via agent-scope relaxed atomics (sc0/sc1 -> coherent point,
//     bypassing the non-coherent per-XCD L2s).  32KB/step/wg read, 512B written.
//   * ordering: clane h atomic-stores -> s_waitcnt vmcnt(0) (implicit in
//     __syncthreads, made explicit) -> barrier -> tid0 relaxed atomicAdd ctr.
//     Reader: tid0 spin on ctr (relaxed agent) -> barrier -> h atomic-loads.
//   * counters were already proven coherent without fences (spin observes
//     increments between polls).
__launch_bounds__(256, 1)
__global__ void k_rec(const f16* __restrict__ Whh,   // [2][2048*512] this layer, dir-major
                      const f16* __restrict__ Xp,    // [8192][4096] f16 (includes bias)
                      f16* __restrict__ hbuf,        // [2][2][32][512] f16
                      unsigned int* __restrict__ ctr,// [2][256][16] u32 (this layer)
                      f16* __restrict__ out16,       // hs0 (layer0) or null
                      float* __restrict__ out32)     // d_out (layer1) or null
{
  __shared__ f16 wl[16 * 512];     // rotated storage
  const int wg = blockIdx.x;
  const int dir = wg >> 7;
  const int w = wg & 127;
  const int tid = threadIdx.x;
  const int wave = tid >> 6;
  const int lane = tid & 63;
  const int bgl = lane & 3;
  const int ks = (lane >> 2) & 15;         // kseg: lane bits 2..5
  const int bg = (wave << 2) | bgl;        // 0..15 (pair of batches)
  const bool clane = (ks == 0);
  const f16* whhd = Whh + ((size_t)dir << 20);

  // load this wg's 16 gate rows into LDS, granule-rotated: slot = (g + kseg) & 3
  #pragma unroll
  for (int i = 0; i < 4; i++) {
    int gl = i * 256 + tid;                 // 1024 granules (16 rows * 64)
    int r = gl >> 6;
    int g6 = gl & 63;
    int kseg = g6 >> 2, g = g6 & 3;
    int slot = (g + kseg) & 3;
    int grow = (r >> 2) * 512 + w * 4 + (r & 3);   // gate*512 + j
    h8 v = *(const h8*)(whhd + (size_t)grow * 512 + g6 * 8);
    *(h8*)(wl + r * 512 + kseg * 32 + slot * 8) = v;
  }
  float c_st[4][2] = {};                    // persistent cell state on clanes
  __syncthreads();

  for (int step = 0; step < SEQT; step++) {
    const int treal = dir ? (SEQT - 1 - step) : step;
    // prefetch Xp (independent of h -> issued before the spin)
    h4v xp[4][2];
    if (clane) {
      #pragma unroll
      for (int bi = 0; bi < 2; bi++) {
        int b = bg * 2 + bi;
        const f16* base = Xp + ((size_t)(b * SEQT + treal)) * NCOL + dir * 2048 + w * 4;
        #pragma unroll
        for (int gate = 0; gate < 4; gate++)
          xp[gate][bi] = *(const h4v*)(base + gate * 512);
      }
    }
    float red[16][2];
    if (step > 0) {
      if (tid == 0) {
        unsigned int* c16 = ctr + ((dir * SEQT + (step - 1)) << 4);
        long it = 0;
        while (true) {
          unsigned int s = 0;
          #pragma unroll
          for (int q = 0; q < 16; q++)
            s += __hip_atomic_load(&c16[q], __ATOMIC_RELAXED, __HIP_MEMORY_SCOPE_AGENT);
          if (s >= 128u) break;
          if (++it > 200000) break;        // safety bound against deadlock
          __builtin_amdgcn_s_sleep(1);
        }
      }
      __syncthreads();
      // direct coherent h load (no LDS round-trip; each thread's slice is
      // disjoint).  Granule rotation matches wl content: hr[bi][(g+ks)&3]
      // holds h[b][ks*32 + g*8 .. +7], same k-range as wl slot (g+ks)&3.
      const f16* hsrc = hbuf + (((size_t)(step & 1) * 2 + dir) * 32) * 512;
      h8 hr[2][4];
      #pragma unroll
      for (int bi = 0; bi < 2; bi++) {
        int b = bg * 2 + bi;
        #pragma unroll
        for (int g = 0; g < 4; g++) {
          const u64* p = (const u64*)(hsrc + (size_t)b * 512 + ks * 32 + g * 8);
          union { h8 v; u64 u[2]; } hu;
          hu.u[0] = __hip_atomic_load(p,     __ATOMIC_RELAXED, __HIP_MEMORY_SCOPE_AGENT);
          hu.u[1] = __hip_atomic_load(p + 1, __ATOMIC_RELAXED, __HIP_MEMORY_SCOPE_AGENT);
          hr[bi][(g + ks) & 3] = hu.v;
        }
      }
      float acc[16][2];
      #pragma unroll
      for (int r = 0; r < 16; r++) { acc[r][0] = 0.f; acc[r][1] = 0.f; }
      #pragma unroll
      for (int r = 0; r < 16; r++) {
        #pragma unroll
        for (int s4 = 0; s4 < 4; s4++) {
          h8 wv = *(const h8*)(wl + r * 512 + ks * 32 + s4 * 8);  // broadcast read
          acc[r][0] = dot8(wv, hr[0][s4], acc[r][0]);
          acc[r][1] = dot8(wv, hr[1][s4], acc[r][1]);
        }
      }
      // full k-reduction in-wave: ks occupies lane bits 2..5
      #pragma unroll
      for (int r = 0; r < 16; r++) {
        #pragma unroll
        for (int bi = 0; bi < 2; bi++) {
          float v = acc[r][bi];
          v += __shfl_xor(v, 4);
          v += __shfl_xor(v, 8);
          v += __shfl_xor(v, 16);
          v += __shfl_xor(v, 32);
          red[r][bi] = v;
        }
      }
    } else {
      #pragma unroll
      for (int r = 0; r < 16; r++) { red[r][0] = 0.f; red[r][1] = 0.f; }
    }
    // gate math + state update on clanes (b = bg*2+bi, 4 j's each)
    if (clane) {
      #pragma unroll
      for (int bi = 0; bi < 2; bi++) {
        int b = bg * 2 + bi;
        h4v hq;
        fx4 ho;
        #pragma unroll
        for (int jq = 0; jq < 4; jq++) {
          float gi = red[0 + jq][bi]  + (float)xp[0][bi][jq];
          float gf = red[4 + jq][bi]  + (float)xp[1][bi][jq];
          float gg = red[8 + jq][bi]  + (float)xp[2][bi][jq];
          float go = red[12 + jq][bi] + (float)xp[3][bi][jq];
          float ig = sigmoidf_(gi);
          float fg = sigmoidf_(gf);
          float og = sigmoidf_(go);
          float tg = tanhf_(gg);
          float cc = fg * c_st[jq][bi] + ig * tg;
          c_st[jq][bi] = cc;
          float hv = og * tanhf_(cc);
          hq[jq] = (f16)hv;
          ho[jq] = hv;
        }
        union { h4v v; u64 u; } su; su.v = hq;
        __hip_atomic_store(
            (u64*)(hbuf + ((((size_t)(step + 1) & 1) * 2 + dir) * 32 + b) * 512 + w * 4),
            su.u, __ATOMIC_RELAXED, __HIP_MEMORY_SCOPE_AGENT);
        if (out16)
          *(h4v*)(out16 + ((size_t)(b * SEQT + treal)) * 1024 + dir * 512 + w * 4) = hq;
        if (out32)
          *(fx4*)(out32 + ((size_t)(b * SEQT + treal)) * 1024 + dir * 512 + w * 4) = ho;
      }
    }
    // drain coherent h stores (explicit; __syncthreads also implies it), then
    // signal.  No cache-wide fence needed: h stores are write-through coherent.
    asm volatile("s_waitcnt vmcnt(0)" ::: "memory");
    __syncthreads();
    if (tid == 0 && step < SEQT - 1)
      atomicAdd(&ctr[((dir * SEQT + step) << 4) + (w >> 3)], 1u);
  }
}

extern "C" void kernel_launch(void* const* d_in, const int* in_sizes, int n_in,
                              void* d_out, int out_size, void* d_ws, size_t ws_size,
                              hipStream_t stream) {
  const float* x       = (const float*)d_in[0];
  const float* emb     = (const float*)d_in[1];
  const float* wih_l0  = (const float*)d_in[2];
  const float* whh_l0  = (const float*)d_in[3];
  const float* bih_l0  = (const float*)d_in[4];
  const float* bhh_l0  = (const float*)d_in[5];
  const float* wih_l0r = (const float*)d_in[6];
  const float* whh_l0r = (const float*)d_in[7];
  const float* bih_l0r = (const float*)d_in[8];
  const float* bhh_l0r = (const float*)d_in[9];
  const float* wih_l1  = (const float*)d_in[10];
  const float* whh_l1  = (const float*)d_in[11];
  const float* bih_l1  = (const float*)d_in[12];
  const float* bhh_l1  = (const float*)d_in[13];
  const float* wih_l1r = (const float*)d_in[14];
  const float* whh_l1r = (const float*)d_in[15];
  const float* bih_l1r = (const float*)d_in[16];
  const float* bhh_l1r = (const float*)d_in[17];
  const int*   dom     = (const int*)d_in[18];
  float* out = (float*)d_out;
  char* ws = (char*)d_ws;
  if (ws_size < WS_NEED) return;   // insufficient scratch; bench will flag mismatch

  float* e_vec = (float*)(ws + OFF_E);
  float* biasb = (float*)(ws + OFF_BIAS);
  f16* whh16 = (f16*)(ws + OFF_WHH);
  f16* wih0  = (f16*)(ws + OFF_WIH0);
  f16* wih1  = (f16*)(ws + OFF_WIH1);
  f16* xf16  = (f16*)(ws + OFF_XF16);
  f16* hs0   = (f16*)(ws + OFF_HS0);
  f16* xp    = (f16*)(ws + OFF_XP);
  f16* hbuf  = (f16*)(ws + OFF_HBUF);
  unsigned int* ctr = (unsigned int*)(ws + OFF_CTR);

  hipMemsetAsync(ws + OFF_CTR, 0, 0x10000, stream);
  k_e<<<1, 64, 0, stream>>>(emb, dom, e_vec);
  k_gen_whh<<<16384, 256, 0, stream>>>(whh_l0, whh_l0r, whh_l1, whh_l1r, e_vec, whh16);
  k_gen_wih<<<8192, 256, 0, stream>>>(wih_l0, wih_l0r, e_vec, wih0, 9);
  k_gen_wih<<<16384, 256, 0, stream>>>(wih_l1, wih_l1r, e_vec, wih1, 10);
  k_gen_bias<<<32, 256, 0, stream>>>(bih_l0, bhh_l0, bih_l0r, bhh_l0r,
                                     bih_l1, bhh_l1, bih_l1r, bhh_l1r, e_vec, biasb);
  k_cast<<<4096, 256, 0, stream>>>(x, xf16, 1048576);
  // layer 0
  k_gemm<<<dim3(64, 32), 256, 0, stream>>>(xf16, wih0, biasb, xp, 512);
  k_rec<<<256, 256, 0, stream>>>(whh16, xp, hbuf, ctr, hs0, nullptr);
  // layer 1
  k_gemm<<<dim3(64, 32), 256, 0, stream>>>(hs0, wih1, biasb + 4096, xp, 1024);
  k_rec<<<256, 256, 0, stream>>>(whh16 + ((size_t)2 << 20), xp, hbuf, ctr + 8192,
                                 nullptr, out);
}

// Round 3
// 4010.430 us; speedup vs baseline: 6.8222x; 4.8507x over previous
//
#include <hip/hip_runtime.h>
#include <stdint.h>

typedef _Float16 f16;
typedef _Float16 h8  __attribute__((ext_vector_type(8)));
typedef _Float16 h4v __attribute__((ext_vector_type(4)));
typedef _Float16 h2v __attribute__((ext_vector_type(2)));
typedef float    fx4 __attribute__((ext_vector_type(4)));
typedef unsigned long long u64;

constexpr int HDIM   = 512;
constexpr int SEQT   = 256;
constexpr int NBATCH = 32;
constexpr int NCOL   = 4096;   // 2 dirs * 2048 gate rows

// ---- ws layout (bytes) ----
constexpr size_t OFF_E    = 0;            // 16 f32
constexpr size_t OFF_BIAS = 0x1000;       // 2 layers * 4096 f32
constexpr size_t OFF_WHH  = 0x10000;      // 4 * 2048*512 f16 (layer*2+dir)
constexpr size_t OFF_WIH0 = 0x00900000;   // 4096*512  f16
constexpr size_t OFF_WIH1 = 0x00D00000;   // 4096*1024 f16
constexpr size_t OFF_XF16 = 0x01500000;   // 8192*512  f16
constexpr size_t OFF_HS0  = 0x01D00000;   // 8192*1024 f16 (layer0 output)
constexpr size_t OFF_XP   = 0x02D00000;   // 8192*4096 f16
constexpr size_t OFF_HBUF = 0x06D00000;   // 2*2*32*512 f16 (double-buffered h)
constexpr size_t OFF_CTR  = 0x06D20000;   // counters, 64KB zeroed
constexpr size_t WS_NEED  = 0x06D30000;   // ~109.2 MB

__device__ __forceinline__ float sigmoidf_(float x) { return 1.0f / (1.0f + __expf(-x)); }
__device__ __forceinline__ float tanhf_(float x) {
  float e2 = __expf(2.0f * x);
  return (e2 - 1.0f) / (e2 + 1.0f);
}

// ---- e = renorm(emb_table[domain_id]) ----
__global__ void k_e(const float* __restrict__ emb, const int* __restrict__ dom,
                    float* __restrict__ e_out) {
  int lane = threadIdx.x;
  float v = 0.f;
  int d = *dom;
  if (lane < 16) v = emb[d * 16 + lane];
  float s = v * v;
  s += __shfl_xor(s, 1); s += __shfl_xor(s, 2);
  s += __shfl_xor(s, 4); s += __shfl_xor(s, 8);
  float n = sqrtf(s);
  float scale = fminf(1.0f, 1.0f / fmaxf(n, 1e-7f));
  if (lane < 16) e_out[lane] = v * scale;
}

// ---- Whh generation -> f16, 4 tensors of 2048x512, index = layer*2+dir ----
__global__ void k_gen_whh(const float* __restrict__ s0, const float* __restrict__ s1,
                          const float* __restrict__ s2, const float* __restrict__ s3,
                          const float* __restrict__ e, f16* __restrict__ out) {
  int idx = blockIdx.x * 256 + threadIdx.x;      // 4 * 1048576 total
  int t = idx >> 20;
  int rem = idx & 1048575;                        // g*512 + k
  const float* src = (t == 0) ? s0 : (t == 1) ? s1 : (t == 2) ? s2 : s3;
  const float4* w = (const float4*)(src + (size_t)rem * 16);
  float acc = 0.f;
  #pragma unroll
  for (int q = 0; q < 4; q++) {
    float4 wv = w[q];
    acc += wv.x * e[q*4+0] + wv.y * e[q*4+1] + wv.z * e[q*4+2] + wv.w * e[q*4+3];
  }
  out[idx] = (f16)acc;
}

// ---- Wih generation -> f16 rows n = dir*2048+g, cols K (ksh = log2 K) ----
__global__ void k_gen_wih(const float* __restrict__ sf, const float* __restrict__ sr,
                          const float* __restrict__ e, f16* __restrict__ out, int ksh) {
  int idx = blockIdx.x * 256 + threadIdx.x;      // 4096 * K total
  int n = idx >> ksh;
  int k = idx & ((1 << ksh) - 1);
  int dir = n >> 11;
  int g = n & 2047;
  const float* src = dir ? sr : sf;
  const float4* w = (const float4*)(src + ((size_t)(g << ksh) + k) * 16);
  float acc = 0.f;
  #pragma unroll
  for (int q = 0; q < 4; q++) {
    float4 wv = w[q];
    acc += wv.x * e[q*4+0] + wv.y * e[q*4+1] + wv.z * e[q*4+2] + wv.w * e[q*4+3];
  }
  out[idx] = (f16)acc;
}

// ---- bias generation: out[layer*4096 + dir*2048 + g] = (b_ih+b_hh)·e ----
__global__ void k_gen_bias(const float* bi0, const float* bh0, const float* bi0r, const float* bh0r,
                           const float* bi1, const float* bh1, const float* bi1r, const float* bh1r,
                           const float* __restrict__ e, float* __restrict__ out) {
  int idx = blockIdx.x * 256 + threadIdx.x;      // 8192
  int layer = idx >> 12;
  int dir = (idx >> 11) & 1;
  int g = idx & 2047;
  const float* a; const float* b;
  if (layer == 0) { a = dir ? bi0r : bi0; b = dir ? bh0r : bh0; }
  else            { a = dir ? bi1r : bi1; b = dir ? bh1r : bh1; }
  float acc = 0.f;
  #pragma unroll
  for (int m = 0; m < 16; m++) acc += (a[g*16 + m] + b[g*16 + m]) * e[m];
  out[idx] = acc;
}

// ---- fp32 -> fp16 cast (by float4) ----
__global__ void k_cast(const float* __restrict__ x, f16* __restrict__ out, int n4) {
  int i = blockIdx.x * 256 + threadIdx.x;
  if (i < n4) {
    float4 v = ((const float4*)x)[i];
    h4v o; o[0] = (f16)v.x; o[1] = (f16)v.y; o[2] = (f16)v.z; o[3] = (f16)v.w;
    *(h4v*)(out + (size_t)i * 4) = o;
  }
}

// ---- GEMM: C[m][n] = sum_k A[m][k]*B[n][k] + bias[n], A:(8192,K) B:(4096,K) f16, C f16 ----
__launch_bounds__(256, 2)
__global__ void k_gemm(const f16* __restrict__ A, const f16* __restrict__ B,
                       const float* __restrict__ bias, f16* __restrict__ C, int K) {
  __shared__ f16 Al[128 * 64];
  __shared__ f16 Bl[128 * 64];
  const int tid = threadIdx.x;
  const int m0 = blockIdx.x * 128;
  const int n0 = blockIdx.y * 128;
  const int lane = tid & 63, wave = tid >> 6;
  const int wm = (wave >> 1) * 64, wn = (wave & 1) * 64;
  const int quad = lane >> 4, m16 = lane & 15;
  const int r_row = tid >> 3;
  const int r_c8 = tid & 7;
  fx4 acc[4][4] = {};
  for (int kb = 0; kb < K; kb += 64) {
    h8 ra[4], rb[4];
    #pragma unroll
    for (int r = 0; r < 4; r++) {
      int row = r * 32 + r_row;
      int c8 = r_c8 ^ (row & 7);
      ra[r] = *(const h8*)(A + (size_t)(m0 + row) * K + kb + c8 * 8);
      rb[r] = *(const h8*)(B + (size_t)(n0 + row) * K + kb + c8 * 8);
    }
    __syncthreads();
    #pragma unroll
    for (int r = 0; r < 4; r++) {
      *(h8*)(Al + (r * 256 + tid) * 8) = ra[r];
      *(h8*)(Bl + (r * 256 + tid) * 8) = rb[r];
    }
    __syncthreads();
    #pragma unroll
    for (int kk = 0; kk < 2; kk++) {
      h8 af[4], bf[4];
      #pragma unroll
      for (int i = 0; i < 4; i++) {
        int arow = wm + i * 16 + m16;
        int slot = (kk * 4 + quad) ^ (arow & 7);
        af[i] = *(const h8*)(Al + arow * 64 + slot * 8);
      }
      #pragma unroll
      for (int j = 0; j < 4; j++) {
        int brow = wn + j * 16 + m16;
        int slot = (kk * 4 + quad) ^ (brow & 7);
        bf[j] = *(const h8*)(Bl + brow * 64 + slot * 8);
      }
      #pragma unroll
      for (int i = 0; i < 4; i++)
        #pragma unroll
        for (int j = 0; j < 4; j++)
          acc[i][j] = __builtin_amdgcn_mfma_f32_16x16x32_f16(af[i], bf[j], acc[i][j], 0, 0, 0);
    }
  }
  // epilogue: D[m = quad*4+reg][n = m16]
  #pragma unroll
  for (int j = 0; j < 4; j++) {
    int n = n0 + wn + j * 16 + m16;
    float bv = bias[n];
    #pragma unroll
    for (int i = 0; i < 4; i++) {
      int mbase = m0 + wm + i * 16 + quad * 4;
      #pragma unroll
      for (int rr = 0; rr < 4; rr++)
        C[(size_t)(mbase + rr) * NCOL + n] = (f16)(acc[i][j][rr] + bv);
    }
  }
}

// ---- persistent recurrence kernel: 32 wgs (16 per direction), MFMA-based ----
// wg = dir*16 + c.  CU c owns j in [c*32, c*32+32), all 4 gates = 128 Whh rows.
// Whh rows held PERSISTENTLY in registers as A-fragments (rloc = jj*4+gate
// ordering => each lane's 4 C-regs are exactly the i,f,g,o gates of one
// (jj,batch) cell -> lane-local gate math, zero shuffles).
// Per step: coherent coop-load h (32KB) -> LDS -> B-frags -> 64 MFMA/wave.
// Gate outputs staged in LDS, then ONE coalesced 8B agent-atomic store per
// thread (was 1024 scattered 2B stores).  Sync: relaxed agent atomics only;
// one counter per (dir,step); vmcnt(0) drain -> barrier -> tid0 signal.
__launch_bounds__(256, 1)
__global__ void k_rec(const f16* __restrict__ Whh,   // [2][2048*512] this layer, dir-major
                      const f16* __restrict__ Xp,    // [8192][4096] f16 (includes bias)
                      f16* __restrict__ hbuf,        // [2][2][32][512] f16
                      unsigned int* __restrict__ ctr,// per-layer: [2][256] u32 (stride 1)
                      f16* __restrict__ out16,       // hs0 (layer0) or null
                      float* __restrict__ out32)     // d_out (layer1) or null
{
  __shared__ f16 hl[32 * 520];             // h staging (in), padded stride 520
  __shared__ f16 hs16[32 * 32];            // h staging (out), [b][jloc]
  __shared__ float hs32[32 * 32];          // f32 out staging, [b][jloc]
  const int wg  = blockIdx.x;              // 0..31
  const int dir = wg >> 4;
  const int c   = wg & 15;
  const int tid = threadIdx.x;
  const int w   = tid >> 6;                // wave 0..3
  const int lane = tid & 63;
  const int col  = lane & 15;              // batch col / row-in-tile
  const int quad = lane >> 4;              // 0..3
  const f16* whhd = Whh + ((size_t)dir << 20);

  // ---- persistent A fragments: Whh rows -> registers (128 VGPR) ----
  // wave w owns m-tiles {2w, 2w+1} = local rows [32w, 32w+32)
  h8 af[2][16];
  #pragma unroll
  for (int mtl = 0; mtl < 2; mtl++) {
    int rloc = (2 * w + mtl) * 16 + col;   // 0..127, rloc = jj*4 + gate
    int jj = rloc >> 2, gate = rloc & 3;
    const f16* rowp = whhd + ((size_t)(gate * 512 + c * 32 + jj)) * 512 + quad * 8;
    #pragma unroll
    for (int kt = 0; kt < 16; kt++)
      af[mtl][kt] = *(const h8*)(rowp + kt * 32);
  }
  // cells: (mtl, nt): jloc = w*8 + quad + mtl*4, b = nt*16 + col
  const int jloc0 = w * 8 + quad;
  const int jbase = c * 32 + jloc0;
  float c_st[2][2] = {};

  for (int step = 0; step < SEQT; step++) {
    const int treal = dir ? (SEQT - 1 - step) : step;
    // ---- Xp prefetch (independent of h; issued before the spin) ----
    float xg[2][2][4];
    #pragma unroll
    for (int mtl = 0; mtl < 2; mtl++) {
      int j = jbase + mtl * 4;
      #pragma unroll
      for (int nt = 0; nt < 2; nt++) {
        int b = nt * 16 + col;
        const f16* base = Xp + ((size_t)(b * SEQT + treal)) * NCOL + dir * 2048 + j;
        #pragma unroll
        for (int g = 0; g < 4; g++) xg[mtl][nt][g] = (float)base[g * 512];
      }
    }
    fx4 acc[2][2] = {};
    if (step > 0) {
      if (tid == 0) {
        unsigned int* cp = ctr + (dir * SEQT + (step - 1));
        long it = 0;
        while (__hip_atomic_load(cp, __ATOMIC_RELAXED, __HIP_MEMORY_SCOPE_AGENT) < 16u) {
          if (++it > 2000000) break;       // safety bound against deadlock
          __builtin_amdgcn_s_sleep(1);
        }
      }
      __syncthreads();
      // ---- coherent coop-load h[32][512] -> LDS (stride 520) ----
      {
        const f16* hsrc = hbuf + ((size_t)((step & 1) * 2 + dir)) * 32 * 512;
        int b = tid >> 3, seg = tid & 7;   // 128B per thread
        const u64* gp = (const u64*)(hsrc + b * 512 + seg * 64);
        u64 hv[16];
        #pragma unroll
        for (int q = 0; q < 16; q++)
          hv[q] = __hip_atomic_load(gp + q, __ATOMIC_RELAXED, __HIP_MEMORY_SCOPE_AGENT);
        f16* dst = hl + b * 520 + seg * 64;
        #pragma unroll
        for (int q = 0; q < 16; q++)
          *(u64*)(dst + q * 4) = hv[q];
      }
      __syncthreads();
      // ---- B-frags from LDS + MFMA: D[row=gate-row][col=batch] ----
      #pragma unroll
      for (int kt = 0; kt < 16; kt++) {
        h8 bf[2];
        #pragma unroll
        for (int nt = 0; nt < 2; nt++)
          bf[nt] = *(const h8*)(hl + (nt * 16 + col) * 520 + kt * 32 + quad * 8);
        #pragma unroll
        for (int mtl = 0; mtl < 2; mtl++)
          #pragma unroll
          for (int nt = 0; nt < 2; nt++)
            acc[mtl][nt] = __builtin_amdgcn_mfma_f32_16x16x32_f16(
                af[mtl][kt], bf[nt], acc[mtl][nt], 0, 0, 0);
      }
    }
    // ---- lane-local gate math -> LDS staging ----
    #pragma unroll
    for (int mtl = 0; mtl < 2; mtl++) {
      int jloc = jloc0 + mtl * 4;
      #pragma unroll
      for (int nt = 0; nt < 2; nt++) {
        int b = nt * 16 + col;
        float gi = acc[mtl][nt][0] + xg[mtl][nt][0];
        float gf = acc[mtl][nt][1] + xg[mtl][nt][1];
        float gg = acc[mtl][nt][2] + xg[mtl][nt][2];
        float go = acc[mtl][nt][3] + xg[mtl][nt][3];
        float ig = sigmoidf_(gi);
        float fg = sigmoidf_(gf);
        float og = sigmoidf_(go);
        float tg = tanhf_(gg);
        float cc = fg * c_st[mtl][nt] + ig * tg;
        c_st[mtl][nt] = cc;
        float hv = og * tanhf_(cc);
        hs16[b * 32 + jloc] = (f16)hv;
        if (out32) hs32[b * 32 + jloc] = hv;
      }
    }
    __syncthreads();                        // staging visible to all waves
    // ---- coalesced coherent h store + output stores (1 u64 / thread) ----
    {
      int b = tid >> 3, qq = tid & 7;       // 4 j's per thread
      u64 pv = *(const u64*)(hs16 + b * 32 + qq * 4);
      f16* hdst = hbuf + ((size_t)(((step + 1) & 1) * 2 + dir)) * 32 * 512;
      __hip_atomic_store((u64*)(hdst + (size_t)b * 512 + c * 32 + qq * 4), pv,
                         __ATOMIC_RELAXED, __HIP_MEMORY_SCOPE_AGENT);
      if (out16)
        *(u64*)(out16 + ((size_t)(b * SEQT + treal)) * 1024 + dir * 512 + c * 32 + qq * 4) = pv;
      if (out32) {
        float4 ov = *(const float4*)(hs32 + b * 32 + qq * 4);
        *(float4*)(out32 + ((size_t)(b * SEQT + treal)) * 1024 + dir * 512 + c * 32 + qq * 4) = ov;
      }
    }
    // drain coherent stores (per-thread), barrier, then single signal
    asm volatile("s_waitcnt vmcnt(0)" ::: "memory");
    __syncthreads();
    if (tid == 0 && step < SEQT - 1)
      atomicAdd(&ctr[dir * SEQT + step], 1u);
  }
}

extern "C" void kernel_launch(void* const* d_in, const int* in_sizes, int n_in,
                              void* d_out, int out_size, void* d_ws, size_t ws_size,
                              hipStream_t stream) {
  const float* x       = (const float*)d_in[0];
  const float* emb     = (const float*)d_in[1];
  const float* wih_l0  = (const float*)d_in[2];
  const float* whh_l0  = (const float*)d_in[3];
  const float* bih_l0  = (const float*)d_in[4];
  const float* bhh_l0  = (const float*)d_in[5];
  const float* wih_l0r = (const float*)d_in[6];
  const float* whh_l0r = (const float*)d_in[7];
  const float* bih_l0r = (const float*)d_in[8];
  const float* bhh_l0r = (const float*)d_in[9];
  const float* wih_l1  = (const float*)d_in[10];
  const float* whh_l1  = (const float*)d_in[11];
  const float* bih_l1  = (const float*)d_in[12];
  const float* bhh_l1  = (const float*)d_in[13];
  const float* wih_l1r = (const float*)d_in[14];
  const float* whh_l1r = (const float*)d_in[15];
  const float* bih_l1r = (const float*)d_in[16];
  const float* bhh_l1r = (const float*)d_in[17];
  const int*   dom     = (const int*)d_in[18];
  float* out = (float*)d_out;
  char* ws = (char*)d_ws;
  if (ws_size < WS_NEED) return;   // insufficient scratch; bench will flag mismatch

  float* e_vec = (float*)(ws + OFF_E);
  float* biasb = (float*)(ws + OFF_BIAS);
  f16* whh16 = (f16*)(ws + OFF_WHH);
  f16* wih0  = (f16*)(ws + OFF_WIH0);
  f16* wih1  = (f16*)(ws + OFF_WIH1);
  f16* xf16  = (f16*)(ws + OFF_XF16);
  f16* hs0   = (f16*)(ws + OFF_HS0);
  f16* xp    = (f16*)(ws + OFF_XP);
  f16* hbuf  = (f16*)(ws + OFF_HBUF);
  unsigned int* ctr = (unsigned int*)(ws + OFF_CTR);

  hipMemsetAsync(ws + OFF_CTR, 0, 0x10000, stream);
  k_e<<<1, 64, 0, stream>>>(emb, dom, e_vec);
  k_gen_whh<<<16384, 256, 0, stream>>>(whh_l0, whh_l0r, whh_l1, whh_l1r, e_vec, whh16);
  k_gen_wih<<<8192, 256, 0, stream>>>(wih_l0, wih_l0r, e_vec, wih0, 9);
  k_gen_wih<<<16384, 256, 0, stream>>>(wih_l1, wih_l1r, e_vec, wih1, 10);
  k_gen_bias<<<32, 256, 0, stream>>>(bih_l0, bhh_l0, bih_l0r, bhh_l0r,
                                     bih_l1, bhh_l1, bih_l1r, bhh_l1r, e_vec, biasb);
  k_cast<<<4096, 256, 0, stream>>>(x, xf16, 1048576);
  // layer 0
  k_gemm<<<dim3(64, 32), 256, 0, stream>>>(xf16, wih0, biasb, xp, 512);
  k_rec<<<32, 256, 0, stream>>>(whh16, xp, hbuf, ctr, hs0, nullptr);
  // layer 1
  k_gemm<<<dim3(64, 32), 256, 0, stream>>>(hs0, wih1, biasb + 4096, xp, 1024);
  k_rec<<<32, 256, 0, stream>>>(whh16 + ((size_t)2 << 20), xp, hbuf, ctr + 8192,
                                 nullptr, out);
}